// Round 3
// baseline (1018.536 us; speedup 1.0000x reference)
//
#include <hip/hip_runtime.h>
#include <math.h>

// GCN 2-layer + sigmoid head. CSR pull-gather via direct atomic scatter.
// R18: delete the binned-staging pipeline (k_fillbin + k_sort) entirely.
//  Within-node neighbor order is free (bf16-rounded sums), so classic CSR:
//   k_hist:   deg[dst]++ (6.4M non-returning atomics over 200K words)
//   k_prep:   per-256-node-bucket wave-scan -> rowptr/rowend/cursor in
//             fixed-CAP regions; fused dinv + xdq(bf16) production
//   k_scatter:r = atomicAdd(&cur[dst]); csr[r] = src (int4-batched)
//   k_gat1/2: node-group gathers (16 lanes/node, bf16 payloads L2-resident)

#define TPB 256
#define NBS 8
#define NBKT 256        // nodes per bucket
#define CAP 9216        // bucket region capacity (mean 8192 + ~11 sigma)
#define NWAVE (TPB / 64)
#define MAXGRID 2048    // grid cap for streaming kernels

__device__ __forceinline__ unsigned short f2bf(float f) {
    unsigned u = __float_as_uint(f);
    unsigned r = (u + 0x7FFFu + ((u >> 16) & 1u)) >> 16;  // RNE
    return (unsigned short)r;
}
__device__ __forceinline__ unsigned pk2(float a, float b) {
    return (unsigned)f2bf(a) | ((unsigned)f2bf(b) << 16);
}
#define BFLO(u) __uint_as_float((u) << 16)
#define BFHI(u) __uint_as_float((u) & 0xFFFF0000u)

// in-degree histogram (no returns; contention ~512 ops/line, fully parallel)
__global__ void __launch_bounds__(TPB) k_hist(
        const int* __restrict__ dst, int* __restrict__ deg, int e) {
    int idx = blockIdx.x * TPB + threadIdx.x;
    int stride = gridDim.x * TPB;
    int e4 = e >> 2;
    const int4* d4 = (const int4*)dst;
    for (int i = idx; i < e4; i += stride) {
        int4 d = d4[i];
        atomicAdd(&deg[d.x], 1);
        atomicAdd(&deg[d.y], 1);
        atomicAdd(&deg[d.z], 1);
        atomicAdd(&deg[d.w], 1);
    }
    for (int i = (e4 << 2) + idx; i < e; i += stride)
        atomicAdd(&deg[dst[i]], 1);
}

// per-bucket exclusive scan of deg -> rowptr/rowend/cursor (fixed-CAP regions)
// + per-node dinv and bf16-packed, dinv-prescaled features xdq.
__global__ void __launch_bounds__(TPB) k_prep(
        const int* __restrict__ deg, const float* __restrict__ x,
        int* __restrict__ rowptr, int* __restrict__ rowend,
        int* __restrict__ curn, float* __restrict__ dinv,
        uint4* __restrict__ xdq, int n) {
    __shared__ int wsum[NWAVE];
    int b = blockIdx.x, t = threadIdx.x;
    int i = (b << NBS) + t;
    int v = deg[i];  // 0 for padded nodes (deg memset each launch)
    int lane = t & 63, wid = t >> 6;
    int iv = v;
#pragma unroll
    for (int off = 1; off < 64; off <<= 1) {
        int u = __shfl_up(iv, off);
        if (lane >= off) iv += u;
    }
    if (lane == 63) wsum[wid] = iv;
    __syncthreads();
    int pre = 0;
#pragma unroll
    for (int wq = 0; wq < NWAVE - 1; wq++)
        if (wid > wq) pre += wsum[wq];
    int ex = pre + iv - v;  // exclusive within bucket
    int base = b * CAP;
    rowptr[i] = base + ex;
    rowend[i] = base + ex + v;
    curn[i] = base + ex;
    if (i < n) {
        float di = rsqrtf((float)(v + 1));  // +1: self-loop
        dinv[i] = di;
        uint4 q;
        q.x = pk2(x[i * 6 + 0] * di, x[i * 6 + 1] * di);
        q.y = pk2(x[i * 6 + 2] * di, x[i * 6 + 3] * di);
        q.z = pk2(x[i * 6 + 4] * di, x[i * 6 + 5] * di);
        q.w = 0;
        xdq[i] = q;
    }
}

// direct scatter: slot = atomicAdd(cursor[dst]); csr[slot] = src.
// int4-batched; returning atomics spread over 200K words, latency hidden by
// grid-stride TLP (tiny kernel, high occupancy).
__global__ void __launch_bounds__(TPB) k_scatter(
        const int* __restrict__ src, const int* __restrict__ dst,
        int* __restrict__ curn, int* __restrict__ csr, int e) {
    int idx = blockIdx.x * TPB + threadIdx.x;
    int stride = gridDim.x * TPB;
    int e4 = e >> 2;
    const int4* s4 = (const int4*)src;
    const int4* d4 = (const int4*)dst;
    for (int i = idx; i < e4; i += stride) {
        int4 d = d4[i];
        int4 s = s4[i];
        int r0 = atomicAdd(&curn[d.x], 1);
        int r1 = atomicAdd(&curn[d.y], 1);
        int r2 = atomicAdd(&curn[d.z], 1);
        int r3 = atomicAdd(&curn[d.w], 1);
        csr[r0] = s.x;
        csr[r1] = s.y;
        csr[r2] = s.z;
        csr[r3] = s.w;
    }
    for (int i = (e4 << 2) + idx; i < e; i += stride) {
        int r = atomicAdd(&curn[dst[i]], 1);
        csr[r] = src[i];
    }
}

// layer-1 gather (pre-W1 domain, bf16 payload): 16 lanes/node, 4 nodes/wave.
// epilogue: agg6 (incl self) -> @W1 -> relu(di*.+b1) -> @W2 -> *di -> g2q (bf16)
__global__ void __launch_bounds__(TPB) k_gat1(
        const uint4* __restrict__ xdq, const int* __restrict__ csr,
        const int* __restrict__ rowptr, const int* __restrict__ rowend,
        const float* __restrict__ dinv,
        const float* __restrict__ b1, const float* __restrict__ W1,
        const float* __restrict__ W2, uint2* __restrict__ g2q, int n) {
    __shared__ float w1[96];   // 6 x 16
    __shared__ float w2[128];  // 16 x 8
    __shared__ float bb[16];
    if (threadIdx.x < 96) w1[threadIdx.x] = W1[threadIdx.x];
    if (threadIdx.x < 128) w2[threadIdx.x] = W2[threadIdx.x];
    if (threadIdx.x < 16) bb[threadIdx.x] = b1[threadIdx.x];
    __syncthreads();
    int sub = threadIdx.x & 15;                    // lane within node group
    int i = blockIdx.x * 16 + (threadIdx.x >> 4);  // 16 nodes per block
    bool valid = (i < n);
    int r0 = rowptr[i], r1 = rowend[i];            // padded nodes: r0 == r1
    float a0 = 0.f, a1 = 0.f, a2 = 0.f, a3 = 0.f, a4 = 0.f, a5 = 0.f;
    float c0 = 0.f, c1 = 0.f, c2 = 0.f, c3 = 0.f, c4 = 0.f, c5 = 0.f;
    if (valid && sub == 0) {  // self-loop term
        uint4 q = xdq[i];
        a0 += BFLO(q.x); a1 += BFHI(q.x);
        a2 += BFLO(q.y); a3 += BFHI(q.y);
        a4 += BFLO(q.z); a5 += BFHI(q.z);
    }
    int j = r0 + sub;
    while (j + 16 < r1) {
        uint4 q = xdq[csr[j]];
        uint4 p = xdq[csr[j + 16]];
        a0 += BFLO(q.x); a1 += BFHI(q.x);
        a2 += BFLO(q.y); a3 += BFHI(q.y);
        a4 += BFLO(q.z); a5 += BFHI(q.z);
        c0 += BFLO(p.x); c1 += BFHI(p.x);
        c2 += BFLO(p.y); c3 += BFHI(p.y);
        c4 += BFLO(p.z); c5 += BFHI(p.z);
        j += 32;
    }
    if (j < r1) {
        uint4 q = xdq[csr[j]];
        a0 += BFLO(q.x); a1 += BFHI(q.x);
        a2 += BFLO(q.y); a3 += BFHI(q.y);
        a4 += BFLO(q.z); a5 += BFHI(q.z);
    }
    a0 += c0; a1 += c1; a2 += c2; a3 += c3; a4 += c4; a5 += c5;
#pragma unroll
    for (int m = 1; m <= 8; m <<= 1) {  // reduce within 16-lane node group
        a0 += __shfl_xor(a0, m); a1 += __shfl_xor(a1, m);
        a2 += __shfl_xor(a2, m); a3 += __shfl_xor(a3, m);
        a4 += __shfl_xor(a4, m); a5 += __shfl_xor(a5, m);
    }
    float di = valid ? dinv[i] : 0.f;
    int f = sub;  // lane = hidden feature
    float hf = a0 * w1[f] + a1 * w1[16 + f] + a2 * w1[32 + f]
             + a3 * w1[48 + f] + a4 * w1[64 + f] + a5 * w1[80 + f];
    float tf = fmaxf(di * hf + bb[f], 0.0f);
    float p0 = tf * w2[f * 8 + 0], p1 = tf * w2[f * 8 + 1];
    float p2 = tf * w2[f * 8 + 2], p3 = tf * w2[f * 8 + 3];
    float p4 = tf * w2[f * 8 + 4], p5 = tf * w2[f * 8 + 5];
    float p6 = tf * w2[f * 8 + 6], p7 = tf * w2[f * 8 + 7];
#pragma unroll
    for (int m = 1; m <= 8; m <<= 1) {  // reduce over the 16 f-lanes
        p0 += __shfl_xor(p0, m); p1 += __shfl_xor(p1, m);
        p2 += __shfl_xor(p2, m); p3 += __shfl_xor(p3, m);
        p4 += __shfl_xor(p4, m); p5 += __shfl_xor(p5, m);
        p6 += __shfl_xor(p6, m); p7 += __shfl_xor(p7, m);
    }
    if (valid && sub < 2) {
        float q0 = sub ? p4 : p0, q1 = sub ? p5 : p1;
        float q2 = sub ? p6 : p2, q3 = sub ? p7 : p3;
        uint2 o;
        o.x = pk2(q0 * di, q1 * di);
        o.y = pk2(q2 * di, q3 * di);
        g2q[i * 2 + sub] = o;
    }
}

// layer-2 gather (bf16 payload): 16 lanes/node, 4 nodes/wave.
// fused head: h = relu(dinv*agg8 + b2); out = sigmoid(h @ Wfc + bfc)
__global__ void __launch_bounds__(TPB) k_gat2(
        const uint4* __restrict__ g2q, const int* __restrict__ csr,
        const int* __restrict__ rowptr, const int* __restrict__ rowend,
        const float* __restrict__ dinv,
        const float* __restrict__ b2, const float* __restrict__ Wfc,
        const float* __restrict__ bfc, float* __restrict__ out, int n) {
    __shared__ float w[8];
    __shared__ float bb[8];
    __shared__ float bf;
    if (threadIdx.x < 8) { w[threadIdx.x] = Wfc[threadIdx.x]; bb[threadIdx.x] = b2[threadIdx.x]; }
    if (threadIdx.x == 0) bf = bfc[0];
    __syncthreads();
    int sub = threadIdx.x & 15;
    int i = blockIdx.x * 16 + (threadIdx.x >> 4);
    bool valid = (i < n);
    int r0 = rowptr[i], r1 = rowend[i];
    float a0 = 0.f, a1 = 0.f, a2 = 0.f, a3 = 0.f;
    float a4 = 0.f, a5 = 0.f, a6 = 0.f, a7 = 0.f;
    if (valid && sub == 0) {  // self-loop term
        uint4 q = g2q[i];
        a0 += BFLO(q.x); a1 += BFHI(q.x); a2 += BFLO(q.y); a3 += BFHI(q.y);
        a4 += BFLO(q.z); a5 += BFHI(q.z); a6 += BFLO(q.w); a7 += BFHI(q.w);
    }
    float c0 = 0.f, c1 = 0.f, c2 = 0.f, c3 = 0.f;
    float c4 = 0.f, c5 = 0.f, c6 = 0.f, c7 = 0.f;
    int j = r0 + sub;
    while (j + 16 < r1) {
        uint4 q = g2q[csr[j]];
        uint4 p = g2q[csr[j + 16]];
        a0 += BFLO(q.x); a1 += BFHI(q.x); a2 += BFLO(q.y); a3 += BFHI(q.y);
        a4 += BFLO(q.z); a5 += BFHI(q.z); a6 += BFLO(q.w); a7 += BFHI(q.w);
        c0 += BFLO(p.x); c1 += BFHI(p.x); c2 += BFLO(p.y); c3 += BFHI(p.y);
        c4 += BFLO(p.z); c5 += BFHI(p.z); c6 += BFLO(p.w); c7 += BFHI(p.w);
        j += 32;
    }
    if (j < r1) {
        uint4 q = g2q[csr[j]];
        a0 += BFLO(q.x); a1 += BFHI(q.x); a2 += BFLO(q.y); a3 += BFHI(q.y);
        a4 += BFLO(q.z); a5 += BFHI(q.z); a6 += BFLO(q.w); a7 += BFHI(q.w);
    }
    a0 += c0; a1 += c1; a2 += c2; a3 += c3;
    a4 += c4; a5 += c5; a6 += c6; a7 += c7;
#pragma unroll
    for (int m = 1; m <= 8; m <<= 1) {  // reduce within 16-lane node group
        a0 += __shfl_xor(a0, m); a1 += __shfl_xor(a1, m);
        a2 += __shfl_xor(a2, m); a3 += __shfl_xor(a3, m);
        a4 += __shfl_xor(a4, m); a5 += __shfl_xor(a5, m);
        a6 += __shfl_xor(a6, m); a7 += __shfl_xor(a7, m);
    }
    if (valid && sub == 0) {  // head computed once per node (cheap, no shfl)
        float di = dinv[i];
        float o = bf;
        o += fmaxf(di * a0 + bb[0], 0.0f) * w[0];
        o += fmaxf(di * a1 + bb[1], 0.0f) * w[1];
        o += fmaxf(di * a2 + bb[2], 0.0f) * w[2];
        o += fmaxf(di * a3 + bb[3], 0.0f) * w[3];
        o += fmaxf(di * a4 + bb[4], 0.0f) * w[4];
        o += fmaxf(di * a5 + bb[5], 0.0f) * w[5];
        o += fmaxf(di * a6 + bb[6], 0.0f) * w[6];
        o += fmaxf(di * a7 + bb[7], 0.0f) * w[7];
        out[i] = 1.0f / (1.0f + expf(-o));
    }
}

extern "C" void kernel_launch(void* const* d_in, const int* in_sizes, int n_in,
                              void* d_out, int out_size, void* d_ws, size_t ws_size,
                              hipStream_t stream) {
    const float* x   = (const float*)d_in[0];
    const int*   ei  = (const int*)d_in[1];
    const float* W1  = (const float*)d_in[2];
    const float* b1  = (const float*)d_in[3];
    const float* W2  = (const float*)d_in[4];
    const float* b2  = (const float*)d_in[5];
    const float* Wfc = (const float*)d_in[6];
    const float* bfc = (const float*)d_in[7];
    float* out = (float*)d_out;

    const int n = in_sizes[0] / 6;   // 200000
    const int e = in_sizes[1] / 2;   // 6400000
    const int* src = ei;
    const int* dst = ei + e;
    const int nb = (n + NBKT - 1) >> NBS;  // 782 buckets
    const size_t np = (size_t)nb << NBS;   // padded node count (200192)
    const size_t reg = (size_t)nb * CAP;   // csr region total (7.2M words)

    int* deg    = (int*)d_ws;            // np
    int* curn   = deg + np;              // np
    int* csr    = curn + np;             // reg
    int* rowptr = csr + reg;             // np
    int* rowend = rowptr + np;           // np
    float* dinv = (float*)(rowend + np); // np
    uint4* xdq  = (uint4*)(dinv + np);   // np * 16 B (offset 16B-aligned)
    uint2* g2q  = (uint2*)(xdq + np);    // np * 16 B

    int sgrid = min((e / 4 + TPB - 1) / TPB, MAXGRID);
    int gw = (n + 15) / 16;              // node-group blocks (16 nodes/block)

    hipMemsetAsync(deg, 0, np * sizeof(int), stream);
    k_hist<<<sgrid, TPB, 0, stream>>>(dst, deg, e);
    k_prep<<<nb, TPB, 0, stream>>>(deg, x, rowptr, rowend, curn, dinv, xdq, n);
    k_scatter<<<sgrid, TPB, 0, stream>>>(src, dst, curn, csr, e);
    k_gat1<<<gw, TPB, 0, stream>>>(xdq, csr, rowptr, rowend, dinv, b1, W1, W2, g2q, n);
    k_gat2<<<gw, TPB, 0, stream>>>((const uint4*)g2q, csr, rowptr, rowend, dinv, b2, Wfc, bfc, out, n);
}

// Round 4
// 244.604 us; speedup vs baseline: 4.1640x; 4.1640x over previous
//
#include <hip/hip_runtime.h>
#include <math.h>

// GCN 2-layer + sigmoid head. CSR pull-gather, zero fp32 atomics.
// R19: deterministic binning (R15 structure) with a cheap offset scan.
//  R18 lesson: direct scatter = 393MB write-allocate amplification. Staged
//  binning is mandatory. R16/R17 lesson: contended returning atomics for
//  region allocation cost 60-90us. So: deterministic offsets, computed by
//  a coalesced column-per-thread 2-level scan (no barriers, no LDS):
//   k_fb1:   per-chunk bucket histogram -> C[chunk][nb] (row coalesced)
//   k_scan1: thread t scans bucket-column b over its chunk segment
//            (256 consecutive threads read 1KB contiguous per step)
//   k_scan2: scan 32 segment sums per bucket, fold b*CAP -> segbase, btot
//   k_fillbin: LDS chunk counting-sort, delta = segbase+O-excl (no atomics)
//   k_sort:  full-bucket reg-cached counting sort -> dense csr, dinv, xdq
//   k_gat1/2: node-group gathers (16 lanes/node, bf16 payloads L2-resident)

#define TPB 256
#define NBS 8
#define NBKT 256        // nodes per bucket
#define MAXB 1024       // max buckets (n <= 262144)
#define BPT (MAXB / TPB)
#define CHUNK 4096      // edges per fillbin block
#define EPT (CHUNK / TPB)
#define CAP 9216        // bucket region capacity (mean 8192 + ~11 sigma)
#define RPT (CAP / TPB) // 36 register-cached words per k_sort thread
#define NWAVE (TPB / 64)
#define NSEG 32         // chunk segments for the 2-level offset scan

__device__ __forceinline__ unsigned short f2bf(float f) {
    unsigned u = __float_as_uint(f);
    unsigned r = (u + 0x7FFFu + ((u >> 16) & 1u)) >> 16;  // RNE
    return (unsigned short)r;
}
__device__ __forceinline__ unsigned pk2(float a, float b) {
    return (unsigned)f2bf(a) | ((unsigned)f2bf(b) << 16);
}
#define BFLO(u) __uint_as_float((u) << 16)
#define BFHI(u) __uint_as_float((u) & 0xFFFF0000u)

// per-chunk bucket histogram -> C[chunk][nb] (coalesced row store)
__global__ void __launch_bounds__(TPB) k_fb1(
        const int* __restrict__ dst, int* __restrict__ C, int e, int nb) {
    __shared__ int h[MAXB];
    int t = threadIdx.x;
    int c0 = blockIdx.x * CHUNK;
    int csize = min(e - c0, CHUNK);
#pragma unroll
    for (int k = 0; k < BPT; k++) h[t * BPT + k] = 0;
    __syncthreads();
    if (csize == CHUNK && ((((size_t)(const void*)(dst + c0)) & 15) == 0)) {
        const int4* d4 = (const int4*)(dst + c0);
#pragma unroll
        for (int k = 0; k < EPT / 4; k++) {
            int4 d = d4[t + k * TPB];
            atomicAdd(&h[d.x >> NBS], 1);
            atomicAdd(&h[d.y >> NBS], 1);
            atomicAdd(&h[d.z >> NBS], 1);
            atomicAdd(&h[d.w >> NBS], 1);
        }
    } else {
        for (int i = t; i < csize; i += TPB)
            atomicAdd(&h[dst[c0 + i] >> NBS], 1);
    }
    __syncthreads();
    int* row = C + (size_t)blockIdx.x * nb;
    for (int b = t; b < nb; b += TPB) row[b] = h[b];
}

// level-1: thread t serially scans bucket-column b over chunk segment s.
// Reads/writes are 1KB-contiguous per block-iteration (fully coalesced).
// O[c][b] = exclusive prefix within segment; Sseg[s][b] = segment total.
__global__ void __launch_bounds__(TPB) k_scan1(
        const int* __restrict__ C, int* __restrict__ O, int* __restrict__ Sseg,
        int nchunk, int nb, int cps, int ngrp) {
    int bid = blockIdx.x;
    int s = bid / ngrp, g = bid - s * ngrp;
    int b = g * TPB + threadIdx.x;
    if (b >= nb) return;
    int cbeg = s * cps;
    int cend = min(cbeg + cps, nchunk);
    int run = 0;
#pragma unroll 4
    for (int c = cbeg; c < cend; c++) {
        int v = C[(size_t)c * nb + b];
        O[(size_t)c * nb + b] = run;
        run += v;
    }
    Sseg[s * nb + b] = run;
}

// level-2: per bucket, exclusive scan of NSEG segment sums; fold in b*CAP.
// segbase[s][b] = b*CAP + sum_{s'<s} Sseg[s'][b]; btot[b] = bucket total.
__global__ void __launch_bounds__(TPB) k_scan2(
        const int* __restrict__ Sseg, int* __restrict__ segbase,
        int* __restrict__ btot, int nb) {
    int b = blockIdx.x * TPB + threadIdx.x;
    if (b >= nb) return;
    int run = b * CAP;
#pragma unroll
    for (int s = 0; s < NSEG; s++) {
        segbase[s * nb + b] = run;
        run += Sseg[s * nb + b];
    }
    btot[b] = run - b * CAP;
}

// bin edges into fixed-cap bucket regions. LDS counting sort of the chunk;
// deterministic delta from segbase+O (no atomics). word: ((d&255)<<18)|s
__global__ void __launch_bounds__(TPB) k_fillbin(
        const int* __restrict__ src, const int* __restrict__ dst,
        const int* __restrict__ O, const int* __restrict__ segbase,
        int* __restrict__ binned, int e, int nb, int cps) {
    __shared__ int stage[CHUNK];            // 16 KB, bucket-sorted packed words
    __shared__ unsigned short bs[CHUNK];    // 8 KB, bucket id per sorted slot
    __shared__ int h[MAXB];                 // 4 KB, hist -> stage cursor
    __shared__ int delta[MAXB];             // 4 KB
    __shared__ int wsum[NWAVE];
    int t = threadIdx.x;
    int c0 = blockIdx.x * CHUNK;
    int csize = min(e - c0, CHUNK);
#pragma unroll
    for (int k = 0; k < BPT; k++) h[t * BPT + k] = 0;
    __syncthreads();
    int dreg[EPT], sreg[EPT];
    if (csize == CHUNK && ((((size_t)(const void*)(dst + c0)) & 15) == 0)
                       && ((((size_t)(const void*)(src + c0)) & 15) == 0)) {
        const int4* d4 = (const int4*)(dst + c0);
        const int4* s4 = (const int4*)(src + c0);
#pragma unroll
        for (int k = 0; k < EPT / 4; k++) {
            int4 d = d4[t + k * TPB];
            int4 s = s4[t + k * TPB];
            dreg[4 * k + 0] = d.x; sreg[4 * k + 0] = s.x;
            dreg[4 * k + 1] = d.y; sreg[4 * k + 1] = s.y;
            dreg[4 * k + 2] = d.z; sreg[4 * k + 2] = s.z;
            dreg[4 * k + 3] = d.w; sreg[4 * k + 3] = s.w;
            atomicAdd(&h[d.x >> NBS], 1);
            atomicAdd(&h[d.y >> NBS], 1);
            atomicAdd(&h[d.z >> NBS], 1);
            atomicAdd(&h[d.w >> NBS], 1);
        }
    } else {
#pragma unroll
        for (int k = 0; k < EPT; k++) {
            int idx = t + k * TPB;
            int d = (idx < csize) ? dst[c0 + idx] : -1;
            int s = (idx < csize) ? src[c0 + idx] : 0;
            dreg[k] = d;
            sreg[k] = s;
            if (d >= 0) atomicAdd(&h[d >> NBS], 1);
        }
    }
    __syncthreads();
    // per-thread local prefix over its BPT bins
    int loc[BPT], hreg[BPT];
    int ts = 0;
#pragma unroll
    for (int k = 0; k < BPT; k++) {
        hreg[k] = h[t * BPT + k];
        loc[k] = ts;
        ts += hreg[k];
    }
    // block-wide inclusive scan of ts: wave shfl scan + wave-sum combine
    int lane = t & 63, wid = t >> 6;
    int v = ts;
#pragma unroll
    for (int off = 1; off < 64; off <<= 1) {
        int u = __shfl_up(v, off);
        if (lane >= off) v += u;
    }
    if (lane == 63) wsum[wid] = v;
    __syncthreads();
    int pre = 0;
#pragma unroll
    for (int wq = 0; wq < NWAVE - 1; wq++)
        if (wid > wq) pre += wsum[wq];
    int tbase = pre + v - ts;  // exclusive prefix for this thread's first bin
    // deterministic delta: global slot = segbase[s][b] + O[c][b] + rank
    const int* Orow = O + (size_t)blockIdx.x * nb;
    const int* segrow = segbase + (size_t)(blockIdx.x / cps) * nb;
#pragma unroll
    for (int k = 0; k < BPT; k++) {
        int b = t * BPT + k;
        int ex = tbase + loc[k];
        h[b] = ex;  // stage cursor
        delta[b] = (b < nb) ? (segrow[b] + Orow[b] - ex) : 0;
    }
    __syncthreads();
    // LDS counting sort of the chunk (registers -> LDS only)
#pragma unroll
    for (int k = 0; k < EPT; k++) {
        int d = dreg[k];
        if (d >= 0) {
            int b = d >> NBS;
            int r = atomicAdd(&h[b], 1);
            stage[r] = ((d & (NBKT - 1)) << 18) | sreg[k];
            bs[r] = (unsigned short)b;
        }
    }
    __syncthreads();
    for (int k = t; k < csize; k += TPB)
        binned[delta[bs[k]] + k] = stage[k];
}

// full-bucket counting sort, register-cached (single region read), LDS-staged
// dense csr flush. Also rowptr/rowend/dinv/xdq(bf16).
__global__ void __launch_bounds__(TPB) k_sort(
        const int* __restrict__ binned, const int* __restrict__ btot,
        const float* __restrict__ x, int* __restrict__ csr,
        int* __restrict__ rowptr, int* __restrict__ rowend,
        float* __restrict__ dinv, uint4* __restrict__ xdq, int n) {
    __shared__ int stage[CAP];     // 36 KB
    __shared__ int cnt[NBKT];
    __shared__ int curs[NBKT];
    __shared__ int wsum[NWAVE];
    int b = blockIdx.x, t = threadIdx.x;
    int base = b * CAP;
    int c = btot[b];
    cnt[t] = 0;
    __syncthreads();
    // 1) read region once into registers + histogram
    int w[RPT];
#pragma unroll
    for (int k = 0; k < RPT; k++) {
        int idx = t + k * TPB;               // coalesced
        w[k] = (idx < c) ? binned[base + idx] : -1;
        if (w[k] >= 0) atomicAdd(&cnt[w[k] >> 18], 1);
    }
    __syncthreads();
    // 2) exclusive scan of 256 bins: wave shfl scan + combine (1 barrier)
    int v = cnt[t];
    int lane = t & 63, wid = t >> 6;
    int iv = v;
#pragma unroll
    for (int off = 1; off < 64; off <<= 1) {
        int u = __shfl_up(iv, off);
        if (lane >= off) iv += u;
    }
    if (lane == 63) wsum[wid] = iv;
    __syncthreads();
    int pre = 0;
#pragma unroll
    for (int wq = 0; wq < NWAVE - 1; wq++)
        if (wid > wq) pre += wsum[wq];
    int ex = pre + iv - v;  // exclusive
    curs[t] = ex;
    // 3) per-node outputs
    int i = (b << NBS) + t;
    rowptr[i] = base + ex;
    rowend[i] = base + ex + v;
    if (i < n) {
        float di = rsqrtf((float)(v + 1));
        dinv[i] = di;
        uint4 q;
        q.x = pk2(x[i * 6 + 0] * di, x[i * 6 + 1] * di);
        q.y = pk2(x[i * 6 + 2] * di, x[i * 6 + 3] * di);
        q.z = pk2(x[i * 6 + 4] * di, x[i * 6 + 5] * di);
        q.w = 0;
        xdq[i] = q;
    }
    __syncthreads();
    // 4) scatter from registers into LDS stage (node-sorted order)
#pragma unroll
    for (int k = 0; k < RPT; k++) {
        if (w[k] >= 0) {
            int r = atomicAdd(&curs[w[k] >> 18], 1);
            stage[r] = w[k] & 0x3FFFF;
        }
    }
    __syncthreads();
    // 5) dense flush
    for (int k = t; k < c; k += TPB)
        csr[base + k] = stage[k];
}

// layer-1 gather (pre-W1 domain, bf16 payload): 16 lanes/node, 4 nodes/wave.
// epilogue: agg6 (incl self) -> @W1 -> relu(di*.+b1) -> @W2 -> *di -> g2q (bf16)
__global__ void __launch_bounds__(TPB) k_gat1(
        const uint4* __restrict__ xdq, const int* __restrict__ csr,
        const int* __restrict__ rowptr, const int* __restrict__ rowend,
        const float* __restrict__ dinv,
        const float* __restrict__ b1, const float* __restrict__ W1,
        const float* __restrict__ W2, uint2* __restrict__ g2q, int n) {
    __shared__ float w1[96];   // 6 x 16
    __shared__ float w2[128];  // 16 x 8
    __shared__ float bb[16];
    if (threadIdx.x < 96) w1[threadIdx.x] = W1[threadIdx.x];
    if (threadIdx.x < 128) w2[threadIdx.x] = W2[threadIdx.x];
    if (threadIdx.x < 16) bb[threadIdx.x] = b1[threadIdx.x];
    __syncthreads();
    int sub = threadIdx.x & 15;                    // lane within node group
    int i = blockIdx.x * 16 + (threadIdx.x >> 4);  // 16 nodes per block
    bool valid = (i < n);
    int r0 = rowptr[i], r1 = rowend[i];            // padded nodes: r0 == r1
    float a0 = 0.f, a1 = 0.f, a2 = 0.f, a3 = 0.f, a4 = 0.f, a5 = 0.f;
    float c0 = 0.f, c1 = 0.f, c2 = 0.f, c3 = 0.f, c4 = 0.f, c5 = 0.f;
    if (valid && sub == 0) {  // self-loop term
        uint4 q = xdq[i];
        a0 += BFLO(q.x); a1 += BFHI(q.x);
        a2 += BFLO(q.y); a3 += BFHI(q.y);
        a4 += BFLO(q.z); a5 += BFHI(q.z);
    }
    int j = r0 + sub;
    while (j + 16 < r1) {
        uint4 q = xdq[csr[j]];
        uint4 p = xdq[csr[j + 16]];
        a0 += BFLO(q.x); a1 += BFHI(q.x);
        a2 += BFLO(q.y); a3 += BFHI(q.y);
        a4 += BFLO(q.z); a5 += BFHI(q.z);
        c0 += BFLO(p.x); c1 += BFHI(p.x);
        c2 += BFLO(p.y); c3 += BFHI(p.y);
        c4 += BFLO(p.z); c5 += BFHI(p.z);
        j += 32;
    }
    if (j < r1) {
        uint4 q = xdq[csr[j]];
        a0 += BFLO(q.x); a1 += BFHI(q.x);
        a2 += BFLO(q.y); a3 += BFHI(q.y);
        a4 += BFLO(q.z); a5 += BFHI(q.z);
    }
    a0 += c0; a1 += c1; a2 += c2; a3 += c3; a4 += c4; a5 += c5;
#pragma unroll
    for (int m = 1; m <= 8; m <<= 1) {  // reduce within 16-lane node group
        a0 += __shfl_xor(a0, m); a1 += __shfl_xor(a1, m);
        a2 += __shfl_xor(a2, m); a3 += __shfl_xor(a3, m);
        a4 += __shfl_xor(a4, m); a5 += __shfl_xor(a5, m);
    }
    float di = valid ? dinv[i] : 0.f;
    int f = sub;  // lane = hidden feature
    float hf = a0 * w1[f] + a1 * w1[16 + f] + a2 * w1[32 + f]
             + a3 * w1[48 + f] + a4 * w1[64 + f] + a5 * w1[80 + f];
    float tf = fmaxf(di * hf + bb[f], 0.0f);
    float p0 = tf * w2[f * 8 + 0], p1 = tf * w2[f * 8 + 1];
    float p2 = tf * w2[f * 8 + 2], p3 = tf * w2[f * 8 + 3];
    float p4 = tf * w2[f * 8 + 4], p5 = tf * w2[f * 8 + 5];
    float p6 = tf * w2[f * 8 + 6], p7 = tf * w2[f * 8 + 7];
#pragma unroll
    for (int m = 1; m <= 8; m <<= 1) {  // reduce over the 16 f-lanes
        p0 += __shfl_xor(p0, m); p1 += __shfl_xor(p1, m);
        p2 += __shfl_xor(p2, m); p3 += __shfl_xor(p3, m);
        p4 += __shfl_xor(p4, m); p5 += __shfl_xor(p5, m);
        p6 += __shfl_xor(p6, m); p7 += __shfl_xor(p7, m);
    }
    if (valid && sub < 2) {
        float q0 = sub ? p4 : p0, q1 = sub ? p5 : p1;
        float q2 = sub ? p6 : p2, q3 = sub ? p7 : p3;
        uint2 o;
        o.x = pk2(q0 * di, q1 * di);
        o.y = pk2(q2 * di, q3 * di);
        g2q[i * 2 + sub] = o;
    }
}

// layer-2 gather (bf16 payload): 16 lanes/node, 4 nodes/wave.
// fused head: h = relu(dinv*agg8 + b2); out = sigmoid(h @ Wfc + bfc)
__global__ void __launch_bounds__(TPB) k_gat2(
        const uint4* __restrict__ g2q, const int* __restrict__ csr,
        const int* __restrict__ rowptr, const int* __restrict__ rowend,
        const float* __restrict__ dinv,
        const float* __restrict__ b2, const float* __restrict__ Wfc,
        const float* __restrict__ bfc, float* __restrict__ out, int n) {
    __shared__ float w[8];
    __shared__ float bb[8];
    __shared__ float bf;
    if (threadIdx.x < 8) { w[threadIdx.x] = Wfc[threadIdx.x]; bb[threadIdx.x] = b2[threadIdx.x]; }
    if (threadIdx.x == 0) bf = bfc[0];
    __syncthreads();
    int sub = threadIdx.x & 15;
    int i = blockIdx.x * 16 + (threadIdx.x >> 4);
    bool valid = (i < n);
    int r0 = rowptr[i], r1 = rowend[i];
    float a0 = 0.f, a1 = 0.f, a2 = 0.f, a3 = 0.f;
    float a4 = 0.f, a5 = 0.f, a6 = 0.f, a7 = 0.f;
    if (valid && sub == 0) {  // self-loop term
        uint4 q = g2q[i];
        a0 += BFLO(q.x); a1 += BFHI(q.x); a2 += BFLO(q.y); a3 += BFHI(q.y);
        a4 += BFLO(q.z); a5 += BFHI(q.z); a6 += BFLO(q.w); a7 += BFHI(q.w);
    }
    float c0 = 0.f, c1 = 0.f, c2 = 0.f, c3 = 0.f;
    float c4 = 0.f, c5 = 0.f, c6 = 0.f, c7 = 0.f;
    int j = r0 + sub;
    while (j + 16 < r1) {
        uint4 q = g2q[csr[j]];
        uint4 p = g2q[csr[j + 16]];
        a0 += BFLO(q.x); a1 += BFHI(q.x); a2 += BFLO(q.y); a3 += BFHI(q.y);
        a4 += BFLO(q.z); a5 += BFHI(q.z); a6 += BFLO(q.w); a7 += BFHI(q.w);
        c0 += BFLO(p.x); c1 += BFHI(p.x); c2 += BFLO(p.y); c3 += BFHI(p.y);
        c4 += BFLO(p.z); c5 += BFHI(p.z); c6 += BFLO(p.w); c7 += BFHI(p.w);
        j += 32;
    }
    if (j < r1) {
        uint4 q = g2q[csr[j]];
        a0 += BFLO(q.x); a1 += BFHI(q.x); a2 += BFLO(q.y); a3 += BFHI(q.y);
        a4 += BFLO(q.z); a5 += BFHI(q.z); a6 += BFLO(q.w); a7 += BFHI(q.w);
    }
    a0 += c0; a1 += c1; a2 += c2; a3 += c3;
    a4 += c4; a5 += c5; a6 += c6; a7 += c7;
#pragma unroll
    for (int m = 1; m <= 8; m <<= 1) {  // reduce within 16-lane node group
        a0 += __shfl_xor(a0, m); a1 += __shfl_xor(a1, m);
        a2 += __shfl_xor(a2, m); a3 += __shfl_xor(a3, m);
        a4 += __shfl_xor(a4, m); a5 += __shfl_xor(a5, m);
        a6 += __shfl_xor(a6, m); a7 += __shfl_xor(a7, m);
    }
    if (valid && sub == 0) {  // head computed once per node (cheap, no shfl)
        float di = dinv[i];
        float o = bf;
        o += fmaxf(di * a0 + bb[0], 0.0f) * w[0];
        o += fmaxf(di * a1 + bb[1], 0.0f) * w[1];
        o += fmaxf(di * a2 + bb[2], 0.0f) * w[2];
        o += fmaxf(di * a3 + bb[3], 0.0f) * w[3];
        o += fmaxf(di * a4 + bb[4], 0.0f) * w[4];
        o += fmaxf(di * a5 + bb[5], 0.0f) * w[5];
        o += fmaxf(di * a6 + bb[6], 0.0f) * w[6];
        o += fmaxf(di * a7 + bb[7], 0.0f) * w[7];
        out[i] = 1.0f / (1.0f + expf(-o));
    }
}

extern "C" void kernel_launch(void* const* d_in, const int* in_sizes, int n_in,
                              void* d_out, int out_size, void* d_ws, size_t ws_size,
                              hipStream_t stream) {
    const float* x   = (const float*)d_in[0];
    const int*   ei  = (const int*)d_in[1];
    const float* W1  = (const float*)d_in[2];
    const float* b1  = (const float*)d_in[3];
    const float* W2  = (const float*)d_in[4];
    const float* b2  = (const float*)d_in[5];
    const float* Wfc = (const float*)d_in[6];
    const float* bfc = (const float*)d_in[7];
    float* out = (float*)d_out;

    const int n = in_sizes[0] / 6;   // 200000 (<= 262144 for 18-bit packing)
    const int e = in_sizes[1] / 2;   // 6400000
    const int* src = ei;
    const int* dst = ei + e;
    const int nb = (n + NBKT - 1) >> NBS;  // 782
    const size_t np = (size_t)nb << NBS;   // padded node count (200192)
    const int nblk = (e + CHUNK - 1) / CHUNK;  // 1563 chunks
    const int cps = (nblk + NSEG - 1) / NSEG;  // chunks per segment (49)
    const int ngrp = (nb + TPB - 1) / TPB;     // bucket groups (4)
    const size_t reg = (size_t)nb * CAP;   // bucket-region total (7.2M words)

    int* C       = (int*)d_ws;                 // nblk * nb
    int* O       = C + (size_t)nblk * nb;      // nblk * nb
    int* Sseg    = O + (size_t)nblk * nb;      // NSEG * MAXB
    int* segbase = Sseg + (size_t)NSEG * MAXB; // NSEG * MAXB
    int* btot    = segbase + (size_t)NSEG * MAXB; // MAXB
    int* binned  = btot + MAXB;                // reg
    int* csr     = binned + reg;               // reg
    int* rowptr  = csr + reg;                  // np
    int* rowend  = rowptr + np;                // np
    float* dinv  = (float*)(rowend + np);      // np
    uint4* xdq   = (uint4*)(dinv + np);        // np * 16 B (16B-aligned)
    uint2* g2q   = (uint2*)(xdq + np);         // np * 16 B

    int gw = (n + 15) / 16;              // node-group blocks (16 nodes/block)

    k_fb1<<<nblk, TPB, 0, stream>>>(dst, C, e, nb);
    k_scan1<<<NSEG * ngrp, TPB, 0, stream>>>(C, O, Sseg, nblk, nb, cps, ngrp);
    k_scan2<<<ngrp, TPB, 0, stream>>>(Sseg, segbase, btot, nb);
    k_fillbin<<<nblk, TPB, 0, stream>>>(src, dst, O, segbase, binned, e, nb, cps);
    k_sort<<<nb, TPB, 0, stream>>>(binned, btot, x, csr, rowptr, rowend, dinv, xdq, n);
    k_gat1<<<gw, TPB, 0, stream>>>(xdq, csr, rowptr, rowend, dinv, b1, W1, W2, g2q, n);
    k_gat2<<<gw, TPB, 0, stream>>>((const uint4*)g2q, csr, rowptr, rowend, dinv, b2, Wfc, bfc, out, n);
}